// Round 5
// baseline (429.443 us; speedup 1.0000x reference)
//
#include <hip/hip_runtime.h>

#define BATCH 8
#define DIN   512
#define SEQ   8192
#define ECH   1024   // concatenated conv output channels (fore 512 | back 512)
#define HCH   256    // per-direction hidden channels
#define CL    32     // scan chunk length
#define NCHNK (SEQ / CL)   // 256 chunks per row

typedef __bf16 bf16;
typedef __bf16 bf16x8 __attribute__((ext_vector_type(8)));
typedef __bf16 bf16x4 __attribute__((ext_vector_type(4)));
typedef float  floatx4  __attribute__((ext_vector_type(4)));
typedef float  floatx16 __attribute__((ext_vector_type(16)));

__device__ __forceinline__ void async_ld16(void* lds, const void* g) {
  __builtin_amdgcn_global_load_lds(
      (const __attribute__((address_space(1))) unsigned int*)g,
      (__attribute__((address_space(3))) unsigned int*)lds, 16, 0, 0);
}

__device__ __forceinline__ float bits2f(unsigned u) {
  return __builtin_bit_cast(float, u);
}

// minGRU step: a = sigmoid(-g), bt = sigmoid(g) * (h>=0 ? 1+h : exp(h))
__device__ __forceinline__ void gru_ab(unsigned v, float& a, float& bt) {
  float hh = bits2f(v << 16);
  float g  = bits2f(v & 0xffff0000u);
  float eg = __expf(-g);
  float sg = 1.f / (1.f + eg);   // sigmoid(g)
  a = eg * sg;                    // sigmoid(-g)
  float gv = hh >= 0.f ? 1.f + hh : __expf(hh);
  bt = sg * gv;
}

// ---------------------------------------------------------------------------
// Kernel 1: convert/permute weights to bf16 in MFMA-FRAGMENT-PACKED order.
// Logical weight row n (after (h,gate)-interleave permutation), column k.
// Packed layout: Wf[(n5*32 + g)*512 + lane*8 + j] where n5=n>>5, g=k>>4,
// lane=(n&31)+32*((k>>3)&1), j=k&7  ->  one wave's B-frag = contiguous 1KB.
// ---------------------------------------------------------------------------
__global__ void k_wconv(const float* __restrict__ wf, const float* __restrict__ bfo,
                        const float* __restrict__ wb, const float* __restrict__ bb,
                        bf16* __restrict__ Wf, float* __restrict__ bias) {
  int idx = blockIdx.x * 256 + threadIdx.x;     // 0 .. 1024*512-1
  if (idx < ECH * DIN) {
    int j    = idx & 7;
    int lane = (idx >> 3) & 63;
    int g    = (idx >> 9) & 31;
    int n5   = idx >> 14;
    int n = n5 * 32 + (lane & 31);
    int k = g * 16 + (lane >> 5) * 8 + j;
    int dir = n >> 9, r = n & 511, e = r >> 1, isg = r & 1;
    int s = e + (isg ? HCH : 0);
    const float* w = dir ? wb : wf;
    Wf[idx] = (bf16)w[s * DIN + k];
  }
  if (idx < ECH) {
    int dir = idx >> 9, r = idx & 511, e = r >> 1, isg = r & 1;
    int s = e + (isg ? HCH : 0);
    bias[idx] = (dir ? bb : bfo)[s];
  }
}

// ---------------------------------------------------------------------------
// Kernel 2: tiled transpose + convert  x[b,d,l] fp32 -> xT[b,l,d] bf16
// ---------------------------------------------------------------------------
__global__ void k_xpose(const float* __restrict__ x, bf16* __restrict__ xT) {
  __shared__ float T[64 * 65];
  int t = threadIdx.x;
  int l0 = blockIdx.x * 64;
  int d0 = blockIdx.y * 64;
  int b  = blockIdx.z;
  const float* xb = x + (size_t)b * DIN * SEQ;
#pragma unroll
  for (int p = 0; p < 4; ++p) {
    int dl = (t >> 4) + p * 16;
    int l4 = (t & 15) * 4;
    float4 v = *(const float4*)(xb + (size_t)(d0 + dl) * SEQ + l0 + l4);
    T[dl * 65 + l4 + 0] = v.x;
    T[dl * 65 + l4 + 1] = v.y;
    T[dl * 65 + l4 + 2] = v.z;
    T[dl * 65 + l4 + 3] = v.w;
  }
  __syncthreads();
  bf16* xTb = xT + (size_t)b * SEQ * DIN;
#pragma unroll
  for (int p = 0; p < 2; ++p) {
    int ll = (t >> 3) + p * 32;
    int d8 = (t & 7) * 8;
    bf16x8 h;
#pragma unroll
    for (int j = 0; j < 8; ++j) h[j] = (bf16)T[(d8 + j) * 65 + ll];
    *(bf16x8*)(xTb + (size_t)(l0 + ll) * DIN + d0 + d8) = h;
  }
}

// ---------------------------------------------------------------------------
// Kernel 3: bf16 MFMA GEMM  hg[b,l,n] = sum_d xT[b,l,d] * Wf[n,d] + bias[n]
// 128x128 tile, BK=64, 4 waves, 32x32x16 frags (2x2 per wave).
// A: async global_load_lds -> XOR-swizzled LDS (16 KB/iter).
// B: DIRECT global->VGPR from fragment-packed Wf (no LDS; halves LDS port
//    traffic — the R4 co-bottleneck). Fused epilogue chunk-scan as before.
// ---------------------------------------------------------------------------
__launch_bounds__(256, 4)
__global__ void k_gemm(const bf16* __restrict__ xT, const bf16* __restrict__ Wf,
                       const float* __restrict__ bias, bf16* __restrict__ hg,
                       float* __restrict__ Asum, float* __restrict__ Bsum) {
  __shared__ bf16 lds[16896];       // staging: As[128][64] (16KB); epilogue: Cs[128][132]
  bf16* As = lds;

  int t = threadIdx.x;
  int lane = t & 63, wave = t >> 6;

  // XCD-locality remap: all 8 n-tiles of one l-tile on one XCD.
  int lin = blockIdx.x + 8 * blockIdx.y;   // 0..511
  int xcd = lin & 7;
  int seq = lin >> 3;                      // 0..63
  int ltile = xcd + 8 * (seq >> 3);        // 0..63
  int ntile = seq & 7;
  int n0 = ntile * 128;
  int l0 = ltile * 128;
  int b  = blockIdx.z;

  int l31 = lane & 31, half = lane >> 5;
  int wm = wave >> 1, wn = wave & 1;
  int mb = wm * 64, nb = wn * 64;

  const bf16* gA  = xT + ((size_t)b * SEQ + l0) * DIN;
  const bf16* gBf = Wf + (size_t)((n0 + nb) >> 5) * 16384 + lane * 8;  // frag-packed

  int srow = wave * 32 + (lane >> 3);                       // + q*8 later
  int scol = (((lane & 7) ^ (lane >> 3)) * 8);              // XOR-swizzled source col

  floatx16 acc[2][2];
#pragma unroll
  for (int i = 0; i < 2; ++i)
#pragma unroll
    for (int j = 0; j < 2; ++j)
#pragma unroll
      for (int r = 0; r < 16; ++r) acc[i][j][r] = 0.f;

  for (int kt = 0; kt < DIN / 64; ++kt) {
    int k0 = kt * 64;
    // A staging (async DMA to LDS)
#pragma unroll
    for (int q = 0; q < 4; ++q)
      async_ld16(As + (wave * 32 + q * 8) * 64,
                 gA + (size_t)(srow + q * 8) * DIN + k0 + scol);
    // B fragments straight to VGPRs (coalesced 1KB loads, L2-resident)
    bf16x8 bf8[2][4];
#pragma unroll
    for (int ni = 0; ni < 2; ++ni)
#pragma unroll
      for (int ks = 0; ks < 4; ++ks)
        bf8[ni][ks] = *(const bf16x8*)(gBf + ni * 16384 + (kt * 4 + ks) * 512);
    __syncthreads();
#pragma unroll
    for (int ks = 0; ks < 4; ++ks) {
#pragma unroll
      for (int mi = 0; mi < 2; ++mi) {
        bf16x8 af = *(const bf16x8*)(As + (mb + mi * 32 + l31) * 64 +
                                     (((ks * 2 + half) ^ (lane & 7)) * 8));
        acc[mi][0] = __builtin_amdgcn_mfma_f32_32x32x16_bf16(af, bf8[0][ks],
                                                             acc[mi][0], 0, 0, 0);
        acc[mi][1] = __builtin_amdgcn_mfma_f32_32x32x16_bf16(af, bf8[1][ks],
                                                             acc[mi][1], 0, 0, 0);
      }
    }
    __syncthreads();
  }

  // epilogue: bias add, pack to bf16 in LDS (stride 132), coalesced store.
  // 32x32 C/D layout: col=lane&31, row=(reg&3)+8*(reg>>2)+4*(lane>>5)  [m74/m101]
  float bb2[2];
#pragma unroll
  for (int ni = 0; ni < 2; ++ni) bb2[ni] = bias[n0 + nb + ni * 32 + l31];
  bf16* Cs = lds;  // [128][132]
#pragma unroll
  for (int mi = 0; mi < 2; ++mi)
#pragma unroll
    for (int ni = 0; ni < 2; ++ni)
#pragma unroll
      for (int r = 0; r < 16; ++r) {
        int row = mb + mi * 32 + 4 * half + (r & 3) + 8 * (r >> 2);
        int col = nb + ni * 32 + l31;
        Cs[row * 132 + col] = (bf16)(acc[mi][ni][r] + bb2[ni]);
      }
  __syncthreads();
  bf16* hgb = hg + ((size_t)b * SEQ + l0) * ECH + n0;
#pragma unroll
  for (int p = 0; p < 8; ++p) {
    int row = p * 16 + (t >> 4);
    int seg = t & 15;
    *(bf16x8*)(hgb + (size_t)row * ECH + seg * 8) =
        *(const bf16x8*)(Cs + row * 132 + seg * 8);
  }

  // fused per-chunk minGRU composition
  // wave = chunk within tile (4 chunks of 32), lane = e-pair within tile (64)
  {
    int dirn = ntile >> 2;               // n0 >> 9
    int c = wave, el = lane;
    float A = 1.f, Bc = 0.f;
#pragma unroll 8
    for (int i = 0; i < CL; ++i) {
      int row = c * CL + (dirn ? (CL - 1 - i) : i);
      unsigned v = *(const unsigned*)(Cs + row * 132 + 2 * el);
      float a, bt;
      gru_ab(v, a, bt);
      A *= a;
      Bc = a * Bc + bt;
    }
    int chunkg = ltile * 4 + c;
    int eg = ((n0 & 511) >> 1) + el;
    size_t o = ((size_t)(b * 2 + dirn) * NCHNK + chunkg) * 256 + eg;
    Asum[o] = A;
    Bsum[o] = Bc;
  }
}

// ---------------------------------------------------------------------------
// Kernel 5: single-pass chunk-summary scan -> carry-in per chunk.
// 16 blocks (b,dir) x 256 thr (e); 256 serial steps of coalesced 1KB loads
// (Asum/Bsum are L2/L3-resident, just written by k_gemm).
// ---------------------------------------------------------------------------
__global__ void k_scan2(const float* __restrict__ Asum, const float* __restrict__ Bsum,
                        float* __restrict__ hin) {
  int e = threadIdx.x, row2 = blockIdx.x, dir = row2 & 1;
  size_t base = (size_t)row2 * NCHNK;
  float h = 0.f;
#pragma unroll 8
  for (int i = 0; i < NCHNK; ++i) {
    int c = dir ? (NCHNK - 1 - i) : i;
    size_t o = (base + c) * 256 + e;
    hin[o] = h;
    h = Asum[o] * h + Bsum[o];
  }
}

// ---------------------------------------------------------------------------
// Kernel 6: recompute local scan with carry-in; 512-thread blocks cover both
// directions of one chunk; LDS transpose T[512][33]; coalesced float4 stores.
// ---------------------------------------------------------------------------
__global__ void k_scan3(const bf16* __restrict__ hg, const float* __restrict__ hin,
                        float* __restrict__ out) {
  __shared__ float T[512 * 33];     // 67,584 B -> 2 blocks/CU
  int t = threadIdx.x;              // 0..511
  int chunk = blockIdx.x, b = blockIdx.y;
  int dir = t >> 8;                 // wave-uniform
  int p = t & 255;                  // e-pair within direction
  const bf16* hb = hg + (size_t)b * SEQ * ECH + dir * 512 + 2 * p;
  float h = hin[((size_t)(b * 2 + dir) * NCHNK + chunk) * 256 + p];
  int lbase = chunk * CL;
#pragma unroll 8
  for (int i = 0; i < CL; ++i) {
    int ll = dir ? (CL - 1 - i) : i;
    unsigned v = *(const unsigned*)(hb + (size_t)(lbase + ll) * ECH);
    float a, bt;
    gru_ab(v, a, bt);
    h = a * h + bt;
    T[t * 33 + ll] = h;
  }
  __syncthreads();
  float* ob = out + (size_t)b * 512 * SEQ + lbase;
#pragma unroll
  for (int q = 0; q < 8; ++q) {
    int row = q * 64 + (t >> 3);    // channel
    int c4 = (t & 7) * 4;           // l within chunk
    float4 v4;
    v4.x = T[row * 33 + c4 + 0];
    v4.y = T[row * 33 + c4 + 1];
    v4.z = T[row * 33 + c4 + 2];
    v4.w = T[row * 33 + c4 + 3];
    *(float4*)(ob + (size_t)row * SEQ + c4) = v4;
  }
}

// ---------------------------------------------------------------------------
extern "C" void kernel_launch(void* const* d_in, const int* in_sizes, int n_in,
                              void* d_out, int out_size, void* d_ws, size_t ws_size,
                              hipStream_t stream) {
  const float* x   = (const float*)d_in[0];
  const float* wf  = (const float*)d_in[1];
  const float* bfo = (const float*)d_in[2];
  const float* wb  = (const float*)d_in[3];
  const float* bb  = (const float*)d_in[4];
  float* out = (float*)d_out;
  char* ws = (char*)d_ws;

  // workspace layout (bytes):
  bf16*  xT   = (bf16*)(ws);                       // 67,108,864
  bf16*  hg   = (bf16*)(ws + 67108864);            // 134,217,728
  bf16*  Wfm  = (bf16*)(ws + 201326592);           // 1,048,576 (frag-packed)
  float* bias = (float*)(ws + 202375168);          // 4,096
  float* Asum = (float*)(ws + 202379264);          // 4,194,304
  float* Bsum = (float*)(ws + 206573568);          // 4,194,304
  float* hin  = (float*)(ws + 210767872);          // 4,194,304  (total ~215 MB)

  k_wconv<<<2048, 256, 0, stream>>>(wf, bfo, wb, bb, Wfm, bias);
  k_xpose<<<dim3(SEQ / 64, DIN / 64, BATCH), 256, 0, stream>>>(x, xT);
  k_gemm<<<dim3(ECH / 128, SEQ / 128, BATCH), 256, 0, stream>>>(xT, Wfm, bias, hg,
                                                                Asum, Bsum);
  k_scan2<<<16, 256, 0, stream>>>(Asum, Bsum, hin);
  k_scan3<<<dim3(NCHNK, BATCH), 512, 0, stream>>>(hg, hin, out);
}